// Round 9
// baseline (200.067 us; speedup 1.0000x reference)
//
#include <hip/hip_runtime.h>
#include <hip/hip_bf16.h>

// Chamfer loss: B=8, P=32, N=M=1024, fp32 in, scalar fp32 out.
// Reference quirk: x[bp,m,c] = rp[bp, (3m+c)%M, (3m+c)>>10]  (torch permute+reshape).
//
// R8: occupancy attack, allocator-friendly. Evidence R2-R7: compiler always
// allocates ~60-64 VGPR (its 8-waves/SIMD target); forced caps below that
// scratch-spill (R5/R6: 200MB traffic), big blocks waste it (1 block/CU).
// So: 1024 blocks x 512 threads (4 row-blocks/bp, 256 rows), LDS ~24.5 KB
// (yS 16K + xS 4K + colminI 4K; no rpS - xS built from L2-cached global),
// launch_bounds(512,4) (cap 128, no forced spill). If VGPR<=64: 4 blocks/CU
// = 32 waves/CU, VALU (~22us) and LDS pipe (~20us) finally overlap.
// Inner = R4b's proven lean RB=4 unroll-1 (compiled to 60 VGPR, no scratch).
// Col-mins: LDS atomicMin int keys -> global atomicMin; last block per bp
// decodes + sums (R6-proven correctness machinery).

#define MM 1024
#define NN 1024
#define THREADS 512
#define NWAVES 8              // per block
#define RBLK 4                // row-blocks per bp
#define ROWS_PER_BLOCK 256
#define ROWS_PER_WAVE 32
#define RB 4                  // rows per inner batch
#define CPL 16                // col-chunks per lane
#define FINF 3.4e38f
#define KEY_INIT 0x7F7F7F7F   // memset 0x7F; > any real key

__device__ __forceinline__ int fkey(float f) {          // monotone float->int
    int b = __float_as_int(f);
    return (b >= 0) ? b : (b ^ 0x7FFFFFFF);
}
__device__ __forceinline__ float funkey(int k) {        // involution
    return __int_as_float((k >= 0) ? k : (k ^ 0x7FFFFFFF));
}

template <int CTRL>
__device__ __forceinline__ float dpp_ror_min(float v) {
    int vi = __float_as_int(v);
    int t  = __builtin_amdgcn_update_dpp(vi, vi, CTRL, 0xf, 0xf, true);
    return fminf(v, __int_as_float(t));
}
__device__ __forceinline__ float wave_min64(float v, int xaddr32) {
    v = dpp_ror_min<0x121>(v);   // row_ror:1 (16-lane rows)
    v = dpp_ror_min<0x122>(v);
    v = dpp_ror_min<0x124>(v);
    v = dpp_ror_min<0x128>(v);
    int s = __builtin_amdgcn_ds_swizzle(__float_as_int(v), 0x401F); // xor16
    v = fminf(v, __int_as_float(s));
    int p = __builtin_amdgcn_ds_bpermute(xaddr32, __float_as_int(v));
    return fminf(v, __int_as_float(p));  // xor 32
}

__global__ __launch_bounds__(THREADS, 4)
void chamfer_kernel(const float* __restrict__ nrf,   // (BP,N,3) -> y
                    const float* __restrict__ rp,    // (BP,M,3) -> x (scrambled)
                    float* __restrict__ out,
                    int* __restrict__ wsKeys,        // (BP,NN) col-min keys
                    int* __restrict__ wsCnt,         // (BP) done counters
                    float inv_bpm, float inv_bpn) {
    const int bp   = blockIdx.x >> 2;
    const int rb   = blockIdx.x & 3;
    const int tid  = threadIdx.x;
    const int lane = tid & 63;
    const int wave = tid >> 6;
    const int xaddr32 = ((lane ^ 32) << 2);

    __shared__ float4 yS[NN];             // 16 KB (y, ||y||^2)
    __shared__ float4 xS[ROWS_PER_BLOCK]; //  4 KB (-2x, ||x||^2)
    __shared__ int    colminI[NN];        //  4 KB int-key col mins
    __shared__ float  rowsumS[NWAVES];
    __shared__ int    lastS;

    const float* rpB = rp  + (size_t)bp * MM * 3;
    const float* yB  = nrf + (size_t)bp * NN * 3;
    int* keysB = wsKeys + (size_t)bp * NN;

    // Phase 0: yS (2 cols/thread), colminI init, xS (this block's 256 rows,
    // scrambled view straight from global - L2-cached, one-time).
    #pragma unroll
    for (int t = tid; t < NN; t += THREADS) {
        float a = yB[t * 3 + 0], b = yB[t * 3 + 1], c = yB[t * 3 + 2];
        yS[t] = make_float4(a, b, c, a * a + b * b + c * c);
        colminI[t] = KEY_INIT;
    }
    if (tid < ROWS_PER_BLOCK) {
        const int m = rb * ROWS_PER_BLOCK + tid;
        const int k = 3 * m;
        float a = rpB[((k + 0) & (MM - 1)) * 3 + ((k + 0) >> 10)];
        float b = rpB[((k + 1) & (MM - 1)) * 3 + ((k + 1) >> 10)];
        float c = rpB[((k + 2) & (MM - 1)) * 3 + ((k + 2) >> 10)];
        xS[tid] = make_float4(-2.0f * a, -2.0f * b, -2.0f * c,
                              a * a + b * b + c * c);
    }
    __syncthreads();

    float colmin[CPL];
    #pragma unroll
    for (int i = 0; i < CPL; ++i) colmin[i] = FINF;

    float rowsum = 0.0f;
    const int m0 = wave * ROWS_PER_WAVE;
    for (int r0 = 0; r0 < ROWS_PER_WAVE; r0 += RB) {
        float4 x[RB];
        #pragma unroll
        for (int j = 0; j < RB; ++j) x[j] = xS[m0 + r0 + j];  // broadcast

        float rmin[RB];
        #pragma unroll
        for (int j = 0; j < RB; ++j) rmin[j] = FINF;

        #pragma unroll
        for (int i = 0; i < CPL; ++i) {
            const float4 yv = yS[i * 64 + lane];   // conflict-free b128
            float e[RB];
            #pragma unroll
            for (int j = 0; j < RB; ++j) {
                e[j] = __builtin_fmaf(x[j].x, yv.x,
                        __builtin_fmaf(x[j].y, yv.y,
                         __builtin_fmaf(x[j].z, yv.z, yv.w)));
                rmin[j] = fminf(rmin[j], e[j]);
            }
            float d01 = fminf(e[0] + x[0].w, e[1] + x[1].w);
            float d23 = fminf(e[2] + x[2].w, e[3] + x[3].w);
            colmin[i] = fminf(fminf(colmin[i], d01), d23);  // v_min3
        }

        #pragma unroll
        for (int j = 0; j < RB; ++j) rmin[j] = wave_min64(rmin[j], xaddr32);
        #pragma unroll
        for (int j = 0; j < RB; ++j) rowsum += x[j].w + rmin[j];
    }

    // Per-wave col-min merge into LDS int keys (lane-unique: conflict-free).
    #pragma unroll
    for (int i = 0; i < CPL; ++i)
        atomicMin(&colminI[i * 64 + lane], fkey(colmin[i]));
    if (lane == 0) rowsumS[wave] = rowsum;
    __syncthreads();

    // Global col-min merge + block rowsum.
    #pragma unroll
    for (int t = tid; t < NN; t += THREADS)
        atomicMin(&keysB[t], colminI[t]);
    if (tid == 0) {
        float rs = 0.0f;
        #pragma unroll
        for (int w = 0; w < NWAVES; ++w) rs += rowsumS[w];
        atomicAdd(out, rs * inv_bpm);
        __threadfence();
        lastS = (atomicAdd(&wsCnt[bp], 1) == RBLK - 1);
    }
    __syncthreads();

    // Last block of this bp: decode + sum column mins.
    if (lastS) {
        __threadfence();
        float cs = 0.0f;
        #pragma unroll
        for (int t = tid; t < NN; t += THREADS) {
            int k = atomicMin(&keysB[t], 0x7FFFFFFF);  // device-scope read
            cs += funkey(k);
        }
        #pragma unroll
        for (int off = 32; off > 0; off >>= 1)
            cs += __shfl_xor(cs, off, 64);
        if (lane == 0) rowsumS[wave] = cs;   // reuse
        __syncthreads();
        if (tid == 0) {
            float s = 0.0f;
            #pragma unroll
            for (int w = 0; w < NWAVES; ++w) s += rowsumS[w];
            atomicAdd(out, s * inv_bpn);
        }
    }
}

extern "C" void kernel_launch(void* const* d_in, const int* in_sizes, int n_in,
                              void* d_out, int out_size, void* d_ws, size_t ws_size,
                              hipStream_t stream) {
    const float* nrf = (const float*)d_in[0];  // (B,P,N,3)
    const float* rp  = (const float*)d_in[1];  // (B,P,M,3)
    float* out = (float*)d_out;

    const int BP = in_sizes[1] / (MM * 3);     // 256
    const float inv_bpm = 1.0f / (float)(BP * MM);
    const float inv_bpn = 1.0f / (float)(BP * NN);

    int* wsKeys = (int*)d_ws;                  // BP*NN ints = 1 MB
    int* wsCnt  = wsKeys + (size_t)BP * NN;    // BP ints

    (void)hipMemsetAsync(out, 0, sizeof(float), stream);
    (void)hipMemsetAsync(wsKeys, 0x7F, (size_t)BP * NN * sizeof(int), stream);
    (void)hipMemsetAsync(wsCnt, 0, (size_t)BP * sizeof(int), stream);
    chamfer_kernel<<<BP * RBLK, THREADS, 0, stream>>>(
        nrf, rp, out, wsKeys, wsCnt, inv_bpm, inv_bpn);
}

// Round 10
// 99.910 us; speedup vs baseline: 2.0025x; 2.0025x over previous
//
#include <hip/hip_runtime.h>
#include <hip/hip_bf16.h>

// Chamfer loss: B=8, P=32, N=M=1024, fp32 in, scalar fp32 out.
// Reference quirk: x[bp,m,c] = rp[bp, (3m+c)%M, (3m+c)>>10]  (torch permute+reshape).
//
// R9 = R2 (proven 48.5us: y in per-lane registers, wave owns 64 rows, RB=4)
// with the LDS butterfly replaced by the canonical all-DPP wave64 min
// reduction (row_ror 1/2/4/8 + row_bcast15 mask 0xa + row_bcast31 mask 0xc,
// result in lane 63). R2's ~25us gap over its 20.5us VALU floor was 6144
// ds_swizzle/ds_bpermute chains (~120cyc each) serializing on lgkmcnt;
// this removes ALL hot-loop LDS ops except one x-broadcast per 4 rows.
// Multi-block decompositions falsified 3x (R5/R6/R8): monolithic only.

#define MM 1024
#define NN 1024
#define THREADS 1024
#define NWAVES 16
#define ROWS_PER_WAVE 64
#define RB 4
#define CPL 16                // columns per lane (16*64 = 1024)
#define FINF 3.4e38f

template <int CTRL, int ROW_MASK>
__device__ __forceinline__ float dpp_min(float v) {
    int vi = __float_as_int(v);
    int t  = __builtin_amdgcn_update_dpp(vi, vi, CTRL, ROW_MASK, 0xf, false);
    return fminf(v, __int_as_float(t));
}

// All-DPP wave64 min; lane 63 ends with the full result. Pure VALU.
__device__ __forceinline__ float wave_min64_dpp(float v) {
    v = dpp_min<0x121, 0xf>(v);  // row_ror:1  (16-lane rows)
    v = dpp_min<0x122, 0xf>(v);  // row_ror:2
    v = dpp_min<0x124, 0xf>(v);  // row_ror:4
    v = dpp_min<0x128, 0xf>(v);  // row_ror:8  -> each lane holds its row min
    v = dpp_min<0x142, 0xa>(v);  // row_bcast:15 -> rows 1,3
    v = dpp_min<0x143, 0xc>(v);  // row_bcast:31 -> rows 2,3; lane63 = full
    return v;
}

__global__ __launch_bounds__(THREADS, 4)
void chamfer_kernel(const float* __restrict__ nrf,   // (BP, N, 3) -> y
                    const float* __restrict__ rp,    // (BP, M, 3) -> x (scrambled)
                    float* __restrict__ out,
                    float inv_bpm, float inv_bpn) {
    const int bp   = blockIdx.x;
    const int tid  = threadIdx.x;
    const int lane = tid & 63;
    const int wave = tid >> 6;

    __shared__ float  rpS[MM * 3];            // 12 KB raw rp block
    __shared__ float4 xS[MM];                 // 16 KB per-row (-2x, ||x||^2)
    __shared__ float  colminS[NWAVES][NN];    // 64 KB per-wave col-min partials
    __shared__ float  rowsumS[NWAVES];
    __shared__ float  csumS[NWAVES];

    const float* rpB = rp  + (size_t)bp * MM * 3;
    const float* yB  = nrf + (size_t)bp * NN * 3;

    // Stage rp (coalesced).
    for (int i = tid; i < MM * 3; i += THREADS) rpS[i] = rpB[i];

    // This lane's 16 y-columns into registers.
    float y0[CPL], y1[CPL], y2[CPL], yy[CPL], colmin[CPL];
    #pragma unroll
    for (int i = 0; i < CPL; ++i) {
        int n = i * 64 + lane;
        float a = yB[n * 3 + 0];
        float b = yB[n * 3 + 1];
        float c = yB[n * 3 + 2];
        y0[i] = a; y1[i] = b; y2[i] = c;
        yy[i] = a * a + b * b + c * c;
        colmin[i] = FINF;
    }
    __syncthreads();

    // Per-row x params (one row per thread, scrambled view).
    {
        const int k = 3 * tid;
        float a = rpS[((k + 0) & (MM - 1)) * 3 + ((k + 0) >> 10)];
        float b = rpS[((k + 1) & (MM - 1)) * 3 + ((k + 1) >> 10)];
        float c = rpS[((k + 2) & (MM - 1)) * 3 + ((k + 2) >> 10)];
        xS[tid] = make_float4(-2.0f * a, -2.0f * b, -2.0f * c,
                              a * a + b * b + c * c);
    }
    __syncthreads();

    float rowsum = 0.0f;   // valid in lane 63 only
    const int m0 = wave * ROWS_PER_WAVE;
    for (int r0 = 0; r0 < ROWS_PER_WAVE; r0 += RB) {
        float4 x[RB];
        #pragma unroll
        for (int j = 0; j < RB; ++j) x[j] = xS[m0 + r0 + j];  // broadcast b128

        float rmin[RB];
        #pragma unroll
        for (int j = 0; j < RB; ++j) rmin[j] = FINF;

        #pragma unroll
        for (int i = 0; i < CPL; ++i) {
            const float a = y0[i], b = y1[i], c = y2[i], s = yy[i];
            float e[RB];
            #pragma unroll
            for (int j = 0; j < RB; ++j) {
                e[j] = __builtin_fmaf(x[j].x, a,
                        __builtin_fmaf(x[j].y, b,
                         __builtin_fmaf(x[j].z, c, s)));
                rmin[j] = fminf(rmin[j], e[j]);
            }
            float d01 = fminf(e[0] + x[0].w, e[1] + x[1].w);
            float d23 = fminf(e[2] + x[2].w, e[3] + x[3].w);
            colmin[i] = fminf(fminf(colmin[i], d01), d23);  // v_min3
        }

        // 4 interleaved all-VALU wave-min reductions (no LDS, no lgkmcnt).
        #pragma unroll
        for (int j = 0; j < RB; ++j) rmin[j] = wave_min64_dpp(rmin[j]);
        #pragma unroll
        for (int j = 0; j < RB; ++j) rowsum += x[j].w + rmin[j];
    }

    // Publish per-wave partials (lane 63 holds the true rowsum).
    #pragma unroll
    for (int i = 0; i < CPL; ++i) colminS[wave][i * 64 + lane] = colmin[i];
    if (lane == 63) rowsumS[wave] = rowsum;
    __syncthreads();

    // Cross-wave column-min merge + sum (1 col per thread).
    {
        const int n = tid;
        float cm = colminS[0][n];
        #pragma unroll
        for (int w = 1; w < NWAVES; ++w) cm = fminf(cm, colminS[w][n]);
        float csum = wave_min64_dpp(FINF);  // no-op warm; keep simple below
        csum = cm;
        #pragma unroll
        for (int off = 32; off > 0; off >>= 1)
            csum += __shfl_xor(csum, off, 64);
        if (lane == 0) csumS[wave] = csum;
    }
    __syncthreads();

    if (tid == 0) {
        float rs = 0.0f, cs = 0.0f;
        #pragma unroll
        for (int w = 0; w < NWAVES; ++w) { rs += rowsumS[w]; cs += csumS[w]; }
        atomicAdd(out, rs * inv_bpm + cs * inv_bpn);
    }
}

extern "C" void kernel_launch(void* const* d_in, const int* in_sizes, int n_in,
                              void* d_out, int out_size, void* d_ws, size_t ws_size,
                              hipStream_t stream) {
    const float* nrf = (const float*)d_in[0];  // (B,P,N,3)
    const float* rp  = (const float*)d_in[1];  // (B,P,M,3)
    float* out = (float*)d_out;

    const int BP = in_sizes[1] / (MM * 3);     // 256
    const float inv_bpm = 1.0f / (float)(BP * MM);
    const float inv_bpn = 1.0f / (float)(BP * NN);

    (void)hipMemsetAsync(out, 0, sizeof(float), stream);
    chamfer_kernel<<<BP, THREADS, 0, stream>>>(nrf, rp, out, inv_bpm, inv_bpn);
}